// Round 8
// baseline (34.103 us; speedup 1.0000x reference)
//
#include <hip/hip_runtime.h>

#define NHEADS 8
#define NPTS 4
#define EDIM 256
#define GRIDW 32
#define LTOK 1024  // 32*32
#define NTOK 4096  // 4 * 1024

// ---------------------------------------------------------------------------
// Fully fused kernel: 512 blocks x 8 tokens x 512 threads (8 waves).
//  P1: stage 8 q-rows to LDS
//  P2: offsets+attn GEMV partials, k-sliced, disjoint ps regions (1 barrier)
//  R : reduce partials -> logits
//  P3: softmax + corner weights/indices
//  P4: bilinear gather; tap metadata preloaded to registers, readlane per tap
//      (4 ds_read_b32 per wave instead of 256)
//  P5: projection, wave = k-slice (32 k), lane = col-group; 2-step LDS tree
//  P6: combine + bias + store
// ---------------------------------------------------------------------------
__global__ __launch_bounds__(512) void fused_all_kernel(
    const float* __restrict__ query,   // [NTOK,256]
    const float* __restrict__ refp,    // [NTOK,2]
    const float* __restrict__ W_off,   // [256,64]
    const float* __restrict__ b_off,   // [64]
    const float* __restrict__ W_attn,  // [256,32]
    const float* __restrict__ b_attn,  // [32]
    const float* __restrict__ W_outp,  // [256,256]
    const float* __restrict__ b_out,   // [256]
    float* __restrict__ out)           // [NTOK,256]
{
    const int tb = blockIdx.x * 8;
    const int tid = threadIdx.x;
    const int lane = tid & 63;
    const int wv = tid >> 6;            // wave 0..7

    __shared__ float qs[8][260];        // q rows; reused as gathered rows in P4+
    __shared__ float lg[8][96];         // logits
    __shared__ float cw[8][128];        // corner weights
    __shared__ int   ci[8][128];        // corner row base offsets (elements)
    __shared__ float ps[8192];          // 32KB scratch (GEMV partials / proj tree)

    // ---- P1: stage 8 q-rows ----
    *(float4*)&qs[wv][lane * 4] = *(const float4*)&query[(tb + wv) * EDIM + lane * 4];
    __syncthreads();

    // ---- P2a: offsets GEMV partials -> ps[0..4095]. wave=k-slice, lane=col ----
    {
        const int kbase = wv * 32;
        float a[8] = {};
        #pragma unroll 2
        for (int kk = 0; kk < 32; kk += 4) {
            const int k = kbase + kk;
            const float w0 = W_off[(k + 0) * 64 + lane];
            const float w1 = W_off[(k + 1) * 64 + lane];
            const float w2 = W_off[(k + 2) * 64 + lane];
            const float w3 = W_off[(k + 3) * 64 + lane];
            #pragma unroll
            for (int t = 0; t < 8; ++t) {
                const float4 q4 = *(const float4*)&qs[t][k];   // LDS broadcast
                a[t] = fmaf(q4.x, w0, a[t]);
                a[t] = fmaf(q4.y, w1, a[t]);
                a[t] = fmaf(q4.z, w2, a[t]);
                a[t] = fmaf(q4.w, w3, a[t]);
            }
        }
        #pragma unroll
        for (int t = 0; t < 8; ++t) ps[(wv * 8 + t) * 64 + lane] = a[t];
    }
    // ---- P2b: attn GEMV partials -> ps[4096..8191]. 16 slices x 16 k ----
    {
        const int ks = tid >> 5;          // 0..15
        const int col = tid & 31;
        const int kbase = ks * 16;
        float a[8] = {};
        #pragma unroll
        for (int kk = 0; kk < 16; kk += 4) {
            const int k = kbase + kk;
            const float w0 = W_attn[(k + 0) * 32 + col];
            const float w1 = W_attn[(k + 1) * 32 + col];
            const float w2 = W_attn[(k + 2) * 32 + col];
            const float w3 = W_attn[(k + 3) * 32 + col];
            #pragma unroll
            for (int t = 0; t < 8; ++t) {
                const float4 q4 = *(const float4*)&qs[t][k];
                a[t] = fmaf(q4.x, w0, a[t]);
                a[t] = fmaf(q4.y, w1, a[t]);
                a[t] = fmaf(q4.z, w2, a[t]);
                a[t] = fmaf(q4.w, w3, a[t]);
            }
        }
        #pragma unroll
        for (int t = 0; t < 8; ++t) ps[4096 + (ks * 8 + t) * 32 + col] = a[t];
    }
    __syncthreads();

    // ---- R: reduce partials -> lg ----
    {
        float s = b_off[lane];
        #pragma unroll
        for (int k = 0; k < 8; ++k) s += ps[(k * 8 + wv) * 64 + lane];
        lg[wv][lane] = s;
    }
    if (tid < 256) {
        const int t = tid >> 5;
        const int col = tid & 31;
        float s = b_attn[col];
        #pragma unroll
        for (int k = 0; k < 16; ++k) s += ps[4096 + (k * 8 + t) * 32 + col];
        lg[t][64 + col] = s;
    }
    __syncthreads();

    // ---- P3: softmax + corners. threads 0..255 = 8 tok x 32 samples ----
    if (tid < 256) {
        const int t = tid >> 5;
        const int s = tid & 31;           // s = h*NPTS + p
        const int token = tb + t;
        const int n = token >> 10;
        const int h = s >> 2;
        const float l0 = lg[t][64 + h * 4 + 0];
        const float l1 = lg[t][64 + h * 4 + 1];
        const float l2 = lg[t][64 + h * 4 + 2];
        const float l3 = lg[t][64 + h * 4 + 3];
        const float m  = fmaxf(fmaxf(l0, l1), fmaxf(l2, l3));
        const float denom = __expf(l0 - m) + __expf(l1 - m) + __expf(l2 - m) + __expf(l3 - m);
        const float aw = __expf(lg[t][64 + s] - m) / (denom * (float)NHEADS);

        const float rx = refp[token * 2 + 0];
        const float ry = refp[token * 2 + 1];
        const float x = (rx + lg[t][2 * s + 0]) * 32.0f - 0.5f;
        const float y = (ry + lg[t][2 * s + 1]) * 32.0f - 0.5f;
        const float x0f = floorf(x);
        const float y0f = floorf(y);
        const float wx = x - x0f;
        const float wy = y - y0f;
        const int x0 = (int)x0f;
        const int y0 = (int)y0f;

        const int xi[4] = { x0, x0 + 1, x0, x0 + 1 };
        const int yi[4] = { y0, y0, y0 + 1, y0 + 1 };
        const float wc[4] = { (1.f - wx) * (1.f - wy), wx * (1.f - wy),
                              (1.f - wx) * wy,         wx * wy };
        #pragma unroll
        for (int c = 0; c < 4; ++c) {
            const bool valid = (xi[c] >= 0) & (xi[c] < GRIDW) & (yi[c] >= 0) & (yi[c] < GRIDW);
            cw[t][s * 4 + c] = valid ? (wc[c] * aw) : 0.f;
            ci[t][s * 4 + c] = valid ? ((n * LTOK + yi[c] * GRIDW + xi[c]) * EDIM) : 0;
        }
    }
    __syncthreads();

    // ---- P4: gather. wave wv -> token tb+wv. Metadata in regs + readlane. ----
    {
        const int loff = lane * 4;
        // 4 ds_read_b32 per wave (each lane holds 2 taps' metadata)
        const int   ciA = ci[wv][lane];
        const int   ciB = ci[wv][64 + lane];
        const float cwA = cw[wv][lane];
        const float cwB = cw[wv][64 + lane];

        float4 acc0 = {0.f, 0.f, 0.f, 0.f};
        float4 acc1 = {0.f, 0.f, 0.f, 0.f};
        float4 acc2 = {0.f, 0.f, 0.f, 0.f};
        float4 acc3 = {0.f, 0.f, 0.f, 0.f};

        #pragma unroll
        for (int t = 0; t < 64; ++t) {
            const int sidx = __builtin_amdgcn_readlane(ciA, t);
            const float wt = __int_as_float(__builtin_amdgcn_readlane(__float_as_int(cwA), t));
            const float4 v = *(const float4*)&query[sidx + loff];
            float4& acc = (t & 2) ? ((t & 1) ? acc3 : acc2) : ((t & 1) ? acc1 : acc0);
            acc.x = fmaf(wt, v.x, acc.x);
            acc.y = fmaf(wt, v.y, acc.y);
            acc.z = fmaf(wt, v.z, acc.z);
            acc.w = fmaf(wt, v.w, acc.w);
        }
        #pragma unroll
        for (int t = 0; t < 64; ++t) {
            const int sidx = __builtin_amdgcn_readlane(ciB, t);
            const float wt = __int_as_float(__builtin_amdgcn_readlane(__float_as_int(cwB), t));
            const float4 v = *(const float4*)&query[sidx + loff];
            float4& acc = (t & 2) ? ((t & 1) ? acc3 : acc2) : ((t & 1) ? acc1 : acc0);
            acc.x = fmaf(wt, v.x, acc.x);
            acc.y = fmaf(wt, v.y, acc.y);
            acc.z = fmaf(wt, v.z, acc.z);
            acc.w = fmaf(wt, v.w, acc.w);
        }

        float4 acc;
        acc.x = (acc0.x + acc1.x) + (acc2.x + acc3.x);
        acc.y = (acc0.y + acc1.y) + (acc2.y + acc3.y);
        acc.z = (acc0.z + acc1.z) + (acc2.z + acc3.z);
        acc.w = (acc0.w + acc1.w) + (acc2.w + acc3.w);
        *(float4*)&qs[wv][loff] = acc;     // gathered row wv
    }
    __syncthreads();

    // ---- P5: projection. wave = k-slice (32 k), lane = col-group of 4. ----
    {
        const int kbase = wv * 32;
        const int c0 = lane * 4;

        float4 acc[8];
        #pragma unroll
        for (int r = 0; r < 8; ++r) acc[r] = float4{0.f, 0.f, 0.f, 0.f};

        #pragma unroll 2
        for (int kk = 0; kk < 32; kk += 4) {
            const int k = kbase + kk;
            const float4 w0 = *(const float4*)&W_outp[(k + 0) * EDIM + c0];
            const float4 w1 = *(const float4*)&W_outp[(k + 1) * EDIM + c0];
            const float4 w2 = *(const float4*)&W_outp[(k + 2) * EDIM + c0];
            const float4 w3 = *(const float4*)&W_outp[(k + 3) * EDIM + c0];
            #pragma unroll
            for (int r = 0; r < 8; ++r) {
                const float4 a = *(const float4*)&qs[r][k];    // broadcast b128
                acc[r].x = fmaf(a.x, w0.x, acc[r].x);
                acc[r].y = fmaf(a.x, w0.y, acc[r].y);
                acc[r].z = fmaf(a.x, w0.z, acc[r].z);
                acc[r].w = fmaf(a.x, w0.w, acc[r].w);
                acc[r].x = fmaf(a.y, w1.x, acc[r].x);
                acc[r].y = fmaf(a.y, w1.y, acc[r].y);
                acc[r].z = fmaf(a.y, w1.z, acc[r].z);
                acc[r].w = fmaf(a.y, w1.w, acc[r].w);
                acc[r].x = fmaf(a.z, w2.x, acc[r].x);
                acc[r].y = fmaf(a.z, w2.y, acc[r].y);
                acc[r].z = fmaf(a.z, w2.z, acc[r].z);
                acc[r].w = fmaf(a.z, w2.w, acc[r].w);
                acc[r].x = fmaf(a.w, w3.x, acc[r].x);
                acc[r].y = fmaf(a.w, w3.y, acc[r].y);
                acc[r].z = fmaf(a.w, w3.z, acc[r].z);
                acc[r].w = fmaf(a.w, w3.w, acc[r].w);
            }
        }

        // ---- k-slice reduction tree: slices 4..7 -> ps, then 0..3 add ----
        if (wv >= 4) {
            float* dst = &ps[(wv - 4) * 2048];
            #pragma unroll
            for (int r = 0; r < 8; ++r)
                *(float4*)&dst[r * 256 + c0] = acc[r];
        }
        __syncthreads();
        if (wv < 4) {
            float* dst = &ps[wv * 2048];
            #pragma unroll
            for (int r = 0; r < 8; ++r) {
                float4 p = *(const float4*)&dst[r * 256 + c0];
                p.x += acc[r].x; p.y += acc[r].y;
                p.z += acc[r].z; p.w += acc[r].w;
                *(float4*)&dst[r * 256 + c0] = p;
            }
        }
        __syncthreads();
    }

    // ---- P6: final combine of 4 half-sums + bias, coalesced store ----
    {
        const int c0 = lane * 4;
        const float4 s0 = *(const float4*)&ps[0 * 2048 + wv * 256 + c0];
        const float4 s1 = *(const float4*)&ps[1 * 2048 + wv * 256 + c0];
        const float4 s2 = *(const float4*)&ps[2 * 2048 + wv * 256 + c0];
        const float4 s3 = *(const float4*)&ps[3 * 2048 + wv * 256 + c0];
        const float4 bb = *(const float4*)&b_out[c0];
        float4 o;
        o.x = ((s0.x + s1.x) + (s2.x + s3.x)) + bb.x;
        o.y = ((s0.y + s1.y) + (s2.y + s3.y)) + bb.y;
        o.z = ((s0.z + s1.z) + (s2.z + s3.z)) + bb.z;
        o.w = ((s0.w + s1.w) + (s2.w + s3.w)) + bb.w;
        *(float4*)&out[(tb + wv) * EDIM + c0] = o;
    }
}

extern "C" void kernel_launch(void* const* d_in, const int* in_sizes, int n_in,
                              void* d_out, int out_size, void* d_ws, size_t ws_size,
                              hipStream_t stream) {
    const float* query  = (const float*)d_in[0];
    const float* refp   = (const float*)d_in[1];
    const float* W_off  = (const float*)d_in[2];
    const float* b_off  = (const float*)d_in[3];
    const float* W_attn = (const float*)d_in[4];
    const float* b_attn = (const float*)d_in[5];
    const float* W_out  = (const float*)d_in[6];
    const float* b_out  = (const float*)d_in[7];
    float* out = (float*)d_out;

    fused_all_kernel<<<NTOK / 8, 512, 0, stream>>>(query, refp, W_off, b_off,
                                                   W_attn, b_attn, W_out, b_out, out);
}

// Round 10
// 33.390 us; speedup vs baseline: 1.0214x; 1.0214x over previous
//
#include <hip/hip_runtime.h>

#define NHEADS 8
#define NPTS 4
#define EDIM 256
#define GRIDW 32
#define LTOK 1024  // 32*32
#define NTOK 4096  // 4 * 1024

// ---------------------------------------------------------------------------
// Fully fused kernel: 512 blocks x 8 tokens x 512 threads (8 waves).
//  P2: both GEMVs, wave = k-slice of 32; q read via WAVE-UNIFORM global loads
//      (scalar path, zero LDS). Attn cols duplicated across half-waves.
//  R : reduce k-slice partials -> logits
//  P3: softmax + corner weights/indices
//  P4: bilinear gather; tap metadata in registers + readlane (LDS-light)
//  P5: projection, wave = k-slice (32 k), lane = col-group; 2-step LDS tree
//  P6: combine + bias + store
// ---------------------------------------------------------------------------
__global__ __launch_bounds__(512) void fused_all_kernel(
    const float* __restrict__ query,   // [NTOK,256]
    const float* __restrict__ refp,    // [NTOK,2]
    const float* __restrict__ W_off,   // [256,64]
    const float* __restrict__ b_off,   // [64]
    const float* __restrict__ W_attn,  // [256,32]
    const float* __restrict__ b_attn,  // [32]
    const float* __restrict__ W_outp,  // [256,256]
    const float* __restrict__ b_out,   // [256]
    float* __restrict__ out)           // [NTOK,256]
{
    const int tb = blockIdx.x * 8;
    const int tid = threadIdx.x;
    const int lane = tid & 63;
    const int wv = tid >> 6;            // wave 0..7

    __shared__ float qs[8][260];        // gathered rows (written in P4)
    __shared__ float lg[8][96];         // logits
    __shared__ float cw[8][128];        // corner weights
    __shared__ int   ci[8][128];        // corner row base offsets (elements)
    __shared__ float ps[8192];          // 32KB scratch (GEMV partials / proj tree)

    // ---- P2: offsets+attn GEMV partials. wave = k-slice (32 k). ----
    // q operand is wave-uniform -> scalar loads, no LDS staging at all.
    {
        const int kb = __builtin_amdgcn_readfirstlane(wv * 32);
        const int colA = lane & 31;
        float a[8] = {};   // offsets partials (col = lane)
        float b[8] = {};   // attn partials (col = lane&31, dup across halves)
        #pragma unroll 2
        for (int kk = 0; kk < 32; kk += 4) {
            const int k = kb + kk;
            const float w0 = W_off[(k + 0) * 64 + lane];
            const float w1 = W_off[(k + 1) * 64 + lane];
            const float w2 = W_off[(k + 2) * 64 + lane];
            const float w3 = W_off[(k + 3) * 64 + lane];
            const float v0 = W_attn[(k + 0) * 32 + colA];
            const float v1 = W_attn[(k + 1) * 32 + colA];
            const float v2 = W_attn[(k + 2) * 32 + colA];
            const float v3 = W_attn[(k + 3) * 32 + colA];
            #pragma unroll
            for (int t = 0; t < 8; ++t) {
                const float4 q4 = *(const float4*)&query[(tb + t) * EDIM + k]; // uniform
                a[t] = fmaf(q4.x, w0, a[t]);
                a[t] = fmaf(q4.y, w1, a[t]);
                a[t] = fmaf(q4.z, w2, a[t]);
                a[t] = fmaf(q4.w, w3, a[t]);
                b[t] = fmaf(q4.x, v0, b[t]);
                b[t] = fmaf(q4.y, v1, b[t]);
                b[t] = fmaf(q4.z, v2, b[t]);
                b[t] = fmaf(q4.w, v3, b[t]);
            }
        }
        #pragma unroll
        for (int t = 0; t < 8; ++t) ps[(wv * 8 + t) * 64 + lane] = a[t];
        if (lane < 32) {
            #pragma unroll
            for (int t = 0; t < 8; ++t) ps[4096 + (wv * 8 + t) * 32 + lane] = b[t];
        }
    }
    __syncthreads();

    // ---- R: reduce partials -> lg ----
    {
        float s = b_off[lane];
        #pragma unroll
        for (int k = 0; k < 8; ++k) s += ps[(k * 8 + wv) * 64 + lane];
        lg[wv][lane] = s;
    }
    if (tid < 256) {
        const int t = tid >> 5;
        const int col = tid & 31;
        float s = b_attn[col];
        #pragma unroll
        for (int k = 0; k < 8; ++k) s += ps[4096 + (k * 8 + t) * 32 + col];
        lg[t][64 + col] = s;
    }
    __syncthreads();

    // ---- P3: softmax + corners. threads 0..255 = 8 tok x 32 samples ----
    if (tid < 256) {
        const int t = tid >> 5;
        const int s = tid & 31;           // s = h*NPTS + p
        const int token = tb + t;
        const int n = token >> 10;
        const int h = s >> 2;
        const float l0 = lg[t][64 + h * 4 + 0];
        const float l1 = lg[t][64 + h * 4 + 1];
        const float l2 = lg[t][64 + h * 4 + 2];
        const float l3 = lg[t][64 + h * 4 + 3];
        const float m  = fmaxf(fmaxf(l0, l1), fmaxf(l2, l3));
        const float denom = __expf(l0 - m) + __expf(l1 - m) + __expf(l2 - m) + __expf(l3 - m);
        const float aw = __expf(lg[t][64 + s] - m) / (denom * (float)NHEADS);

        const float rx = refp[token * 2 + 0];
        const float ry = refp[token * 2 + 1];
        const float x = (rx + lg[t][2 * s + 0]) * 32.0f - 0.5f;
        const float y = (ry + lg[t][2 * s + 1]) * 32.0f - 0.5f;
        const float x0f = floorf(x);
        const float y0f = floorf(y);
        const float wx = x - x0f;
        const float wy = y - y0f;
        const int x0 = (int)x0f;
        const int y0 = (int)y0f;

        const int xi[4] = { x0, x0 + 1, x0, x0 + 1 };
        const int yi[4] = { y0, y0, y0 + 1, y0 + 1 };
        const float wc[4] = { (1.f - wx) * (1.f - wy), wx * (1.f - wy),
                              (1.f - wx) * wy,         wx * wy };
        #pragma unroll
        for (int c = 0; c < 4; ++c) {
            const bool valid = (xi[c] >= 0) & (xi[c] < GRIDW) & (yi[c] >= 0) & (yi[c] < GRIDW);
            cw[t][s * 4 + c] = valid ? (wc[c] * aw) : 0.f;
            ci[t][s * 4 + c] = valid ? ((n * LTOK + yi[c] * GRIDW + xi[c]) * EDIM) : 0;
        }
    }
    __syncthreads();

    // ---- P4: gather. wave wv -> token tb+wv. Metadata in regs + readlane. ----
    {
        const int loff = lane * 4;
        const int   ciA = ci[wv][lane];
        const int   ciB = ci[wv][64 + lane];
        const float cwA = cw[wv][lane];
        const float cwB = cw[wv][64 + lane];

        float4 acc0 = {0.f, 0.f, 0.f, 0.f};
        float4 acc1 = {0.f, 0.f, 0.f, 0.f};
        float4 acc2 = {0.f, 0.f, 0.f, 0.f};
        float4 acc3 = {0.f, 0.f, 0.f, 0.f};

        #pragma unroll
        for (int t = 0; t < 64; ++t) {
            const int sidx = __builtin_amdgcn_readlane(ciA, t);
            const float wt = __int_as_float(__builtin_amdgcn_readlane(__float_as_int(cwA), t));
            const float4 v = *(const float4*)&query[sidx + loff];
            float4& acc = (t & 2) ? ((t & 1) ? acc3 : acc2) : ((t & 1) ? acc1 : acc0);
            acc.x = fmaf(wt, v.x, acc.x);
            acc.y = fmaf(wt, v.y, acc.y);
            acc.z = fmaf(wt, v.z, acc.z);
            acc.w = fmaf(wt, v.w, acc.w);
        }
        #pragma unroll
        for (int t = 0; t < 64; ++t) {
            const int sidx = __builtin_amdgcn_readlane(ciB, t);
            const float wt = __int_as_float(__builtin_amdgcn_readlane(__float_as_int(cwB), t));
            const float4 v = *(const float4*)&query[sidx + loff];
            float4& acc = (t & 2) ? ((t & 1) ? acc3 : acc2) : ((t & 1) ? acc1 : acc0);
            acc.x = fmaf(wt, v.x, acc.x);
            acc.y = fmaf(wt, v.y, acc.y);
            acc.z = fmaf(wt, v.z, acc.z);
            acc.w = fmaf(wt, v.w, acc.w);
        }

        float4 acc;
        acc.x = (acc0.x + acc1.x) + (acc2.x + acc3.x);
        acc.y = (acc0.y + acc1.y) + (acc2.y + acc3.y);
        acc.z = (acc0.z + acc1.z) + (acc2.z + acc3.z);
        acc.w = (acc0.w + acc1.w) + (acc2.w + acc3.w);
        *(float4*)&qs[wv][loff] = acc;     // gathered row wv
    }
    __syncthreads();

    // ---- P5: projection. wave = k-slice (32 k), lane = col-group of 4. ----
    {
        const int kbase = wv * 32;
        const int c0 = lane * 4;

        float4 acc[8];
        #pragma unroll
        for (int r = 0; r < 8; ++r) acc[r] = float4{0.f, 0.f, 0.f, 0.f};

        #pragma unroll 2
        for (int kk = 0; kk < 32; kk += 4) {
            const int k = kbase + kk;
            const float4 w0 = *(const float4*)&W_outp[(k + 0) * EDIM + c0];
            const float4 w1 = *(const float4*)&W_outp[(k + 1) * EDIM + c0];
            const float4 w2 = *(const float4*)&W_outp[(k + 2) * EDIM + c0];
            const float4 w3 = *(const float4*)&W_outp[(k + 3) * EDIM + c0];
            #pragma unroll
            for (int r = 0; r < 8; ++r) {
                const float4 a = *(const float4*)&qs[r][k];    // broadcast b128
                acc[r].x = fmaf(a.x, w0.x, acc[r].x);
                acc[r].y = fmaf(a.x, w0.y, acc[r].y);
                acc[r].z = fmaf(a.x, w0.z, acc[r].z);
                acc[r].w = fmaf(a.x, w0.w, acc[r].w);
                acc[r].x = fmaf(a.y, w1.x, acc[r].x);
                acc[r].y = fmaf(a.y, w1.y, acc[r].y);
                acc[r].z = fmaf(a.y, w1.z, acc[r].z);
                acc[r].w = fmaf(a.y, w1.w, acc[r].w);
                acc[r].x = fmaf(a.z, w2.x, acc[r].x);
                acc[r].y = fmaf(a.z, w2.y, acc[r].y);
                acc[r].z = fmaf(a.z, w2.z, acc[r].z);
                acc[r].w = fmaf(a.z, w2.w, acc[r].w);
                acc[r].x = fmaf(a.w, w3.x, acc[r].x);
                acc[r].y = fmaf(a.w, w3.y, acc[r].y);
                acc[r].z = fmaf(a.w, w3.z, acc[r].z);
                acc[r].w = fmaf(a.w, w3.w, acc[r].w);
            }
        }

        // ---- k-slice reduction tree: slices 4..7 -> ps, then 0..3 add ----
        if (wv >= 4) {
            const int base = (wv - 4) * 2048;
            #pragma unroll
            for (int r = 0; r < 8; ++r)
                *(float4*)&ps[base + r * 256 + c0] = acc[r];
        }
        __syncthreads();
        if (wv < 4) {
            const int base = wv * 2048;
            #pragma unroll
            for (int r = 0; r < 8; ++r) {
                float4 p = *(const float4*)&ps[base + r * 256 + c0];
                p.x += acc[r].x; p.y += acc[r].y;
                p.z += acc[r].z; p.w += acc[r].w;
                *(float4*)&ps[base + r * 256 + c0] = p;
            }
        }
        __syncthreads();
    }

    // ---- P6: final combine of 4 half-sums + bias, coalesced store ----
    {
        const int c0 = lane * 4;
        const float4 s0 = *(const float4*)&ps[0 * 2048 + wv * 256 + c0];
        const float4 s1 = *(const float4*)&ps[1 * 2048 + wv * 256 + c0];
        const float4 s2 = *(const float4*)&ps[2 * 2048 + wv * 256 + c0];
        const float4 s3 = *(const float4*)&ps[3 * 2048 + wv * 256 + c0];
        const float4 bb = *(const float4*)&b_out[c0];
        float4 o;
        o.x = ((s0.x + s1.x) + (s2.x + s3.x)) + bb.x;
        o.y = ((s0.y + s1.y) + (s2.y + s3.y)) + bb.y;
        o.z = ((s0.z + s1.z) + (s2.z + s3.z)) + bb.z;
        o.w = ((s0.w + s1.w) + (s2.w + s3.w)) + bb.w;
        *(float4*)&out[(tb + wv) * EDIM + c0] = o;
    }
}

extern "C" void kernel_launch(void* const* d_in, const int* in_sizes, int n_in,
                              void* d_out, int out_size, void* d_ws, size_t ws_size,
                              hipStream_t stream) {
    const float* query  = (const float*)d_in[0];
    const float* refp   = (const float*)d_in[1];
    const float* W_off  = (const float*)d_in[2];
    const float* b_off  = (const float*)d_in[3];
    const float* W_attn = (const float*)d_in[4];
    const float* b_attn = (const float*)d_in[5];
    const float* W_out  = (const float*)d_in[6];
    const float* b_out  = (const float*)d_in[7];
    float* out = (float*)d_out;

    fused_all_kernel<<<NTOK / 8, 512, 0, stream>>>(query, refp, W_off, b_off,
                                                   W_attn, b_attn, W_out, b_out, out);
}